// Round 8
// baseline (147.724 us; speedup 1.0000x reference)
//
#include <hip/hip_runtime.h>

// LocalNonLocal2D v7 = v6 (73us) + register-row-batched LDS reads.
//   Identical structure: 4 waves/block, 32ch/wave, stride-23 halo, ring-4
//   global_load_lds gather staging, counted vmcnt(45/30/15/0), wred atomics.
//   ONLY change: corr/agg read a full 7-tap row into registers double-buffered
//   across di (reads of row di+1 issue while row di's FMAs run) -> 7-deep
//   guaranteed LDS-read pipeline instead of compiler-found ~6-deep pairs.
//   agg's per-component FMA chain split by di parity (oA/oB).

namespace {

constexpr int CN = 4, CC = 128, HT = 80, WD = 80;
constexpr int KK = 7, K2 = 49, PD = 3;
constexpr int TW = 16, TH = 4;            // pixel tile (64 px, lane = pixel)
constexpr int HROW = 23;                  // halo row stride in float4 (odd)
constexpr int HENT = 10 * HROW;           // 230 float4 entries
constexpr int HCHUNK = (HENT * 4 + 63) / 64;  // 15 chunks of 64 floats
constexpr int HPADF = HCHUNK * 64;        // 960 floats per buffer
constexpr int PLANE = HT * WD;            // 6400
constexpr int GSTRIDE = 4 * PLANE;        // one 4-channel group step
constexpr int OUT_ELEMS = CN * CC * PLANE;
constexpr int NW = 4, GPW = 8;            // 4 waves x 32 ch (8 groups of 4)
constexpr int WR = 53;                    // wred row stride (odd)

__device__ __forceinline__ void make_off(int* off, int bx, int by, int lane) {
#pragma unroll
  for (int q = 0; q < HCHUNK; ++q) {
    int f = q * 64 + lane;
    int e = f >> 2;
    if (e > HENT - 1) e = HENT - 1;   // tail-pad lanes re-load last entry
    const int ch = f & 3;
    const int r  = e / HROW;
    const int cl = e - r * HROW;      // 0..22; col 22 = row pad, never read
    int gh = by * TH - PD + r;
    gh = gh < 0 ? 0 : (gh > HT - 1 ? HT - 1 : gh);
    int gw = bx * TW - PD + cl;
    gw = gw < 0 ? 0 : (gw > WD - 1 ? WD - 1 : gw);
    off[q] = ch * PLANE + gh * WD + gw;  // clamped; OOB taps zeroed later
  }
}

__device__ __forceinline__ void issue_chunks(const float* gbase, const int* off,
                                             float* lds) {
#if __has_builtin(__builtin_amdgcn_global_load_lds)
#pragma unroll
  for (int q = 0; q < HCHUNK; ++q) {
    __builtin_amdgcn_global_load_lds(
        (const __attribute__((address_space(1))) void*)(gbase + off[q]),
        (__attribute__((address_space(3))) void*)(lds + q * 64), 4, 0, 0);
  }
#else
  const int lane = (int)(threadIdx.x & 63);
#pragma unroll
  for (int q = 0; q < HCHUNK; ++q) lds[q * 64 + lane] = gbase[off[q]];
  asm volatile("s_waitcnt lgkmcnt(0)" ::: "memory");
#endif
}

#define WAIT_VM(n_lit)                                      \
  asm volatile("s_waitcnt vmcnt(" #n_lit ")" ::: "memory"); \
  __builtin_amdgcn_sched_barrier(0)

__global__ __launch_bounds__(256) void lnl2d_v7(const float* __restrict__ x,
                                                const float* __restrict__ feat,
                                                float* __restrict__ dout) {
  __shared__ float halo[NW * 4][HPADF];   // 61440 B (ring of 4 per wave)
  __shared__ float wred[64][WR];          // 13568 B
  __shared__ float inv[64];               // 256 B -> 75.3 KB, 2 blocks/CU

  const int tid  = (int)threadIdx.x;
  const int wv   = tid >> 6;
  const int lane = tid & 63;
  const int tx = lane & (TW - 1), ty = lane >> 4;
  const int bx = (int)blockIdx.x, by = (int)blockIdx.y, n = (int)blockIdx.z;
  const int h = by * TH + ty, w = bx * TW + tx;

  const float* xw = x + (size_t)n * CC * PLANE + (size_t)wv * 32 * PLANE;
  const float* fw = feat + (size_t)n * CC * PLANE + (size_t)wv * 32 * PLANE;
  float* out = dout;
  float* pw  = dout + OUT_ELEMS;

  int off[HCHUNK];
  make_off(off, bx, by, lane);

  // init wred; barrier before any atomics land (vmcnt==0 here: free drain)
#pragma unroll
  for (int i = 0; i < (64 * WR + 255) / 256; ++i) {
    const int idx = i * 256 + tid;
    if (idx < 64 * WR) ((float*)wred)[idx] = 0.f;
  }
  __syncthreads();

  float* hb[4] = {halo[wv * 4 + 0], halo[wv * 4 + 1], halo[wv * 4 + 2],
                  halo[wv * 4 + 3]};

  // ---------------- phase 1: per-wave partial correlation ------------------
  float acc[K2];
#pragma unroll
  for (int k = 0; k < K2; ++k) acc[k] = 0.f;

  // Row-batched, register-double-buffered: while FMA-ing row di, the 7 reads
  // of row di+1 are already issued into the other buffer.
  auto corr = [&](const float* b) {
    const float4* h4 = (const float4*)b;
    const float4 c4 = h4[(ty + PD) * HROW + tx + PD];
    float4 rA[KK], rB[KK];
#pragma unroll
    for (int dj = 0; dj < KK; ++dj) rA[dj] = h4[ty * HROW + tx + dj];
#pragma unroll
    for (int di = 0; di < KK; ++di) {
      const float4* cur = (di & 1) ? rB : rA;
      float4* nxt = (di & 1) ? rA : rB;
      if (di < KK - 1) {
#pragma unroll
        for (int dj = 0; dj < KK; ++dj)
          nxt[dj] = h4[(ty + di + 1) * HROW + tx + dj];
      }
#pragma unroll
      for (int dj = 0; dj < KK; ++dj) {
        const float4 n4 = cur[dj];
        acc[di * KK + dj] +=
            c4.x * n4.x + c4.y * n4.y + c4.z * n4.z + c4.w * n4.w;
      }
    }
  };

  issue_chunks(xw + 0 * GSTRIDE, off, hb[0]);
  issue_chunks(xw + 1 * GSTRIDE, off, hb[1]);
  issue_chunks(xw + 2 * GSTRIDE, off, hb[2]);
#pragma unroll
  for (int g = 0; g < GPW; ++g) {
    if (g < GPW - 3) issue_chunks(xw + (g + 3) * GSTRIDE, off, hb[(g + 3) & 3]);
    if (g < GPW - 3)      { WAIT_VM(45); }
    else if (g == GPW - 3){ WAIT_VM(30); }
    else if (g == GPW - 2){ WAIT_VM(15); }
    else                  { WAIT_VM(0); }
    corr(hb[g & 3]);
  }

  // zero OOB taps (zero-padding semantics), cross-wave reduce in LDS
#pragma unroll
  for (int di = 0; di < KK; ++di)
#pragma unroll
    for (int dj = 0; dj < KK; ++dj) {
      const int hh = h + di - PD, ww = w + dj - PD;
      if ((unsigned)hh >= (unsigned)HT || (unsigned)ww >= (unsigned)WD)
        acc[di * KK + dj] = 0.f;
    }
#pragma unroll
  for (int k = 0; k < K2; ++k) atomicAdd(&wred[lane][k], acc[k]);

  __syncthreads();  // vmcnt==0 here (phase 1 drained): free barrier

  // ---- feat prologue first, normalize math under its latency --------------
  issue_chunks(fw + 0 * GSTRIDE, off, hb[0]);
  issue_chunks(fw + 1 * GSTRIDE, off, hb[1]);
  issue_chunks(fw + 2 * GSTRIDE, off, hb[2]);

  float wk[K2];
  float ssum = 0.f;
#pragma unroll
  for (int k = 0; k < K2; ++k) { wk[k] = wred[lane][k]; ssum += wk[k]; }
  const float invs = 1.0f / ssum;
#pragma unroll
  for (int k = 0; k < K2; ++k) wk[k] *= invs;
  if (wv == 0) inv[lane] = invs;

  // ---------------- phase 2: per-wave aggregation over feat ----------------
  float4 ov[GPW];
#pragma unroll
  for (int g = 0; g < GPW; ++g) ov[g] = make_float4(0.f, 0.f, 0.f, 0.f);

  auto agg = [&](const float* b, float4& o) {
    const float4* h4 = (const float4*)b;
    float4 rA[KK], rB[KK];
    float4 oA = make_float4(0.f, 0.f, 0.f, 0.f);
    float4 oB = make_float4(0.f, 0.f, 0.f, 0.f);
#pragma unroll
    for (int dj = 0; dj < KK; ++dj) rA[dj] = h4[ty * HROW + tx + dj];
#pragma unroll
    for (int di = 0; di < KK; ++di) {
      const float4* cur = (di & 1) ? rB : rA;
      float4* nxt = (di & 1) ? rA : rB;
      if (di < KK - 1) {
#pragma unroll
        for (int dj = 0; dj < KK; ++dj)
          nxt[dj] = h4[(ty + di + 1) * HROW + tx + dj];
      }
      float4& oo = (di & 1) ? oB : oA;  // split serial FMA chain by parity
#pragma unroll
      for (int dj = 0; dj < KK; ++dj) {
        const float4 n4 = cur[dj];
        const float f = wk[di * KK + dj];
        oo.x += f * n4.x; oo.y += f * n4.y; oo.z += f * n4.z; oo.w += f * n4.w;
      }
    }
    o.x += oA.x + oB.x; o.y += oA.y + oB.y;
    o.z += oA.z + oB.z; o.w += oA.w + oB.w;
  };

#pragma unroll
  for (int g = 0; g < GPW; ++g) {
    if (g < GPW - 3) issue_chunks(fw + (g + 3) * GSTRIDE, off, hb[(g + 3) & 3]);
    if (g < GPW - 3)      { WAIT_VM(45); }
    else if (g == GPW - 3){ WAIT_VM(30); }
    else if (g == GPW - 2){ WAIT_VM(15); }
    else                  { WAIT_VM(0); }
    agg(hb[g & 3], ov[g]);
  }

  const size_t ob = (size_t)n * CC * PLANE + (size_t)wv * 32 * PLANE +
                    (size_t)(h * WD + w);
#pragma unroll
  for (int g = 0; g < GPW; ++g) {
    out[ob + (size_t)(4 * g + 0) * PLANE] = ov[g].x;
    out[ob + (size_t)(4 * g + 1) * PLANE] = ov[g].y;
    out[ob + (size_t)(4 * g + 2) * PLANE] = ov[g].z;
    out[ob + (size_t)(4 * g + 3) * PLANE] = ov[g].w;
  }

  __syncthreads();  // wred/inv stable for the cooperative pairwise store

  // ---- pairwise_weight (n,h,w,k): 784 contiguous floats per tile row ------
#pragma unroll
  for (int r = 0; r < TH; ++r) {
    float* seg = pw + (size_t)(n * PLANE + (by * TH + r) * WD + bx * TW) * K2;
#pragma unroll
    for (int i = 0; i < (TW * K2) / 256; ++i) {  // 3 full chunks of 256
      const int idx = i * 256 + tid;
      const int col = idx / K2, k = idx - col * K2;
      seg[idx] = wred[r * TW + col][k] * inv[r * TW + col];
    }
    const int rem = TW * K2 - 256 * ((TW * K2) / 256);  // 16
    if (tid < rem) {
      const int idx = 256 * ((TW * K2) / 256) + tid;
      const int col = idx / K2, k = idx - col * K2;
      seg[idx] = wred[r * TW + col][k] * inv[r * TW + col];
    }
  }
}

}  // namespace

extern "C" void kernel_launch(void* const* d_in, const int* in_sizes, int n_in,
                              void* d_out, int out_size, void* d_ws, size_t ws_size,
                              hipStream_t stream) {
  const float* x    = (const float*)d_in[0];
  const float* feat = (const float*)d_in[1];
  float* out        = (float*)d_out;
  dim3 grid(WD / TW, HT / TH, CN);  // (5, 20, 4) = 400 blocks x 256 threads
  lnl2d_v7<<<grid, 256, 0, stream>>>(x, feat, out);
}